// Round 3
// baseline (253.515 us; speedup 1.0000x reference)
//
#include <hip/hip_runtime.h>

#define Bn 128
#define Dd 32
#define Pp 13
#define Ee 16
#define Hh 4
#define HDim 4
#define Ll 416           // Dd*Pp
#define Rr (Bn*Ll)       // 53248 rows

// ---------------------------------------------------------------------------
// Kernel A: fused encoder + QKV. 256 threads, 64 rows per block, 832 blocks.
//  stage0: coop-load 64x64 board tile into LDS (coalesced float4).
//  phase1: wave w owns rows w*16..w*16+15; lane = hidden unit; w1 column in
//          66 VGPRs (coalesced preload); feats via LDS broadcast reads.
//  phase2a: lane = row, wave g computes enc dims 4g..4g+3 (sh stride 65,
//          se stride 17 -> conflict-free).
//  phase2b: lane = row, wave g computes q/k/v[h][hd=g] for h=0..3.
// Q pre-scaled by 0.5*log2(e) so attention uses raw exp2.
// ---------------------------------------------------------------------------
__global__ __launch_bounds__(256, 4) void enc_qkv_kernel(
    const float* __restrict__ board, const float* __restrict__ w1,
    const float* __restrict__ b1, const float* __restrict__ w2,
    const float* __restrict__ b2, const float* __restrict__ w_qkv,
    const float* __restrict__ b_qkv,
    float* __restrict__ Q, float* __restrict__ K, float* __restrict__ V)
{
    __shared__ float4 tile[64][16];   // 16 KB board tile (broadcast reads)
    __shared__ float  sh[64 * 65];    // h, stride 65 (conflict-free)
    __shared__ float  se[64 * 17];    // enc, stride 17 (conflict-free)

    const int tid  = threadIdx.x;
    const int row0 = blockIdx.x * 64;

    // ---- stage 0: cooperative coalesced board tile load ----
    {
        const float4* bsrc = (const float4*)(board + (size_t)row0 * 64);
        #pragma unroll
        for (int kk = 0; kk < 4; ++kk) {
            const int idx = tid + 256 * kk;       // 0..1023
            tile[idx >> 4][idx & 15] = bsrc[idx];
        }
    }
    __syncthreads();

    const int w    = tid >> 6;   // wave id 0..3
    const int lane = tid & 63;

    // ---- phase 1: h = relu(feats @ w1 + b1), lane = hidden unit ----
    {
        float wcol[66];
        #pragma unroll
        for (int i = 0; i < 66; ++i) wcol[i] = w1[i * 64 + lane];
        const float bias1 = b1[lane];

        #pragma unroll 2
        for (int rr = 0; rr < 16; ++rr) {
            const int r   = w * 16 + rr;
            const int row = row0 + r;
            const int b   = row / Ll;
            const int l   = row - b * Ll;
            const int d   = l / Pp;
            const int p   = l - d * Pp;
            float acc = bias1;
            #pragma unroll
            for (int c = 0; c < 16; ++c) {
                const float4 f = tile[r][c];      // broadcast LDS read
                acc = fmaf(f.x, wcol[4 * c + 0], acc);
                acc = fmaf(f.y, wcol[4 * c + 1], acc);
                acc = fmaf(f.z, wcol[4 * c + 2], acc);
                acc = fmaf(f.w, wcol[4 * c + 3], acc);
            }
            acc = fmaf((float)p, wcol[64], acc);
            acc = fmaf((float)d, wcol[65], acc);
            sh[r * 65 + lane] = fmaxf(acc, 0.0f);
        }
    }
    __syncthreads();

    // ---- phase 2a: enc dims 4g..4g+3 for all 64 rows; lane = row ----
    {
        const int g = w;
        float4 e4 = ((const float4*)b2)[g];
        const float4* w2v = (const float4*)w2;
        #pragma unroll 4
        for (int j = 0; j < 64; ++j) {
            const float hj = sh[lane * 65 + j];           // conflict-free
            const float4 w4 = w2v[j * 4 + g];             // uniform, L1-hot
            e4.x = fmaf(hj, w4.x, e4.x);
            e4.y = fmaf(hj, w4.y, e4.y);
            e4.z = fmaf(hj, w4.z, e4.z);
            e4.w = fmaf(hj, w4.w, e4.w);
        }
        se[lane * 17 + 4 * g + 0] = e4.x;
        se[lane * 17 + 4 * g + 1] = e4.y;
        se[lane * 17 + 4 * g + 2] = e4.z;
        se[lane * 17 + 4 * g + 3] = e4.w;
    }
    __syncthreads();

    // ---- phase 2b: lane = row; wave g -> hd = g for q,k,v x h=0..3 ----
    {
        const int g = w;
        float x[16];
        #pragma unroll
        for (int e = 0; e < 16; ++e) x[e] = se[lane * 17 + e];

        const int row = row0 + lane;
        const int b   = row / Ll;
        const int l   = row - b * Ll;
        const float SC = 0.72134752044f;   // 0.5 * log2(e)

        #pragma unroll
        for (int h = 0; h < 4; ++h) {
            const int jq = 4 * h + g;
            const int jk = 16 + 4 * h + g;
            const int jv = 32 + 4 * h + g;
            float aq = b_qkv[jq], ak = b_qkv[jk], av = b_qkv[jv];
            const float4* wq = (const float4*)(w_qkv + jq * 16);
            const float4* wk = (const float4*)(w_qkv + jk * 16);
            const float4* wv = (const float4*)(w_qkv + jv * 16);
            #pragma unroll
            for (int c = 0; c < 4; ++c) {
                const float4 q4 = wq[c], k4 = wk[c], v4 = wv[c];
                aq = fmaf(x[4*c+0], q4.x, aq); aq = fmaf(x[4*c+1], q4.y, aq);
                aq = fmaf(x[4*c+2], q4.z, aq); aq = fmaf(x[4*c+3], q4.w, aq);
                ak = fmaf(x[4*c+0], k4.x, ak); ak = fmaf(x[4*c+1], k4.y, ak);
                ak = fmaf(x[4*c+2], k4.z, ak); ak = fmaf(x[4*c+3], k4.w, ak);
                av = fmaf(x[4*c+0], v4.x, av); av = fmaf(x[4*c+1], v4.y, av);
                av = fmaf(x[4*c+2], v4.z, av); av = fmaf(x[4*c+3], v4.w, av);
            }
            const size_t base = ((size_t)(b * Hh + h) * Ll + l) * HDim + g;
            Q[base] = aq * SC;
            K[base] = ak;
            V[base] = av;
        }
    }
}

// ---------------------------------------------------------------------------
// Kernel B: attention. Grid (512 bh, 2 q-halves) x 256 threads = 4 waves/SIMD.
// K/V staged in LDS (broadcast reads); 1 q-row per thread (208 active).
// Max-free single-pass softmax (scores tiny; softmax shift-invariant).
// ---------------------------------------------------------------------------
__global__ __launch_bounds__(256, 4) void attn_kernel(
    const float* __restrict__ Q, const float* __restrict__ K,
    const float* __restrict__ V, float* __restrict__ ATT)
{
    __shared__ float4 sk[Ll];
    __shared__ float4 sv[Ll];

    const int bh  = blockIdx.x;           // b*Hh + h
    const int half = blockIdx.y;          // 0/1
    const int tid = threadIdx.x;

    const float4* Kb = (const float4*)(K + (size_t)bh * Ll * HDim);
    const float4* Vb = (const float4*)(V + (size_t)bh * Ll * HDim);
    for (int i = tid; i < Ll; i += 256) { sk[i] = Kb[i]; sv[i] = Vb[i]; }
    __syncthreads();

    if (tid >= 208) return;
    const int qi = half * 208 + tid;      // covers 0..415 over the 2 halves

    const float4 q = ((const float4*)(Q + (size_t)bh * Ll * HDim))[qi];
    float s = 0.f;
    float4 o = make_float4(0.f, 0.f, 0.f, 0.f);

    #pragma unroll 4
    for (int l = 0; l < Ll; ++l) {
        const float4 k = sk[l];           // broadcast
        const float4 v = sv[l];           // broadcast
        float dot = q.x * k.x;
        dot = fmaf(q.y, k.y, dot);
        dot = fmaf(q.z, k.z, dot);
        dot = fmaf(q.w, k.w, dot);
        const float e = __builtin_amdgcn_exp2f(dot);
        s += e;
        o.x = fmaf(e, v.x, o.x);
        o.y = fmaf(e, v.y, o.y);
        o.z = fmaf(e, v.z, o.z);
        o.w = fmaf(e, v.w, o.w);
    }

    const int b = bh >> 2;
    const int h = bh & 3;
    const float inv = 1.0f / s;
    float4* dst = (float4*)(ATT + ((size_t)(b * Ll + qi)) * Ee + h * HDim);
    *dst = make_float4(o.x * inv, o.y * inv, o.z * inv, o.w * inv);
}

// ---------------------------------------------------------------------------
// Kernel C: out projection (16x16 GEMV per row; LDS-transposed w_out).
// ---------------------------------------------------------------------------
__global__ __launch_bounds__(256, 8) void outproj_kernel(
    const float* __restrict__ ATT, const float* __restrict__ w_out,
    const float* __restrict__ b_out, float* __restrict__ out)
{
    __shared__ float sx[256];
    __shared__ float sw[256];   // sw[e*16+o] = w_out[o*16+e]

    const int tid = threadIdx.x;
    const size_t gbase = (size_t)blockIdx.x * 256;
    sx[tid] = ATT[gbase + tid];
    sw[tid] = w_out[(tid & 15) * 16 + (tid >> 4)];
    __syncthreads();

    const int rloc = tid >> 4;
    const int o = tid & 15;
    float acc = b_out[o];
    #pragma unroll
    for (int e = 0; e < 16; ++e)
        acc = fmaf(sx[rloc * 16 + e], sw[e * 16 + o], acc);
    out[gbase + tid] = acc;
}

// ---------------------------------------------------------------------------
extern "C" void kernel_launch(void* const* d_in, const int* in_sizes, int n_in,
                              void* d_out, int out_size, void* d_ws, size_t ws_size,
                              hipStream_t stream) {
    const float* board = (const float*)d_in[0];
    const float* w1    = (const float*)d_in[1];
    const float* b1    = (const float*)d_in[2];
    const float* w2    = (const float*)d_in[3];
    const float* b2    = (const float*)d_in[4];
    const float* w_qkv = (const float*)d_in[5];
    const float* b_qkv = (const float*)d_in[6];
    const float* w_out = (const float*)d_in[7];
    const float* b_out = (const float*)d_in[8];
    float* out = (float*)d_out;

    float* ws  = (float*)d_ws;
    float* Q   = ws;                        // (B,H,L,HD)
    float* K   = ws + (size_t)Rr * Ee;
    float* V   = ws + (size_t)2 * Rr * Ee;
    float* ATT = ws + (size_t)3 * Rr * Ee;  // (B,L,E)

    hipLaunchKernelGGL(enc_qkv_kernel, dim3(Rr / 64), dim3(256), 0, stream,
                       board, w1, b1, w2, b2, w_qkv, b_qkv, Q, K, V);
    hipLaunchKernelGGL(attn_kernel, dim3(Bn * Hh, 2), dim3(256), 0, stream,
                       Q, K, V, ATT);
    hipLaunchKernelGGL(outproj_kernel, dim3((Rr * Ee) / 256), dim3(256), 0, stream,
                       ATT, w_out, b_out, out);
}

// Round 4
// 206.979 us; speedup vs baseline: 1.2248x; 1.2248x over previous
//
#include <hip/hip_runtime.h>

#define Bn 128
#define Dd 32
#define Pp 13
#define Ee 16
#define Hh 4
#define HDim 4
#define Ll 416           // Dd*Pp
#define Rr (Bn*Ll)       // 53248 rows

// Broadcast lane i's value to all lanes (v_readlane -> SGPR operand).
__device__ __forceinline__ float lane_bcast(float x, int i) {
    return __uint_as_float(__builtin_amdgcn_readlane(__float_as_uint(x), i));
}

// ---------------------------------------------------------------------------
// Kernel A: fused encoder + QKV. 256 threads / 64 rows per block, 832 blocks.
//  phase1: wave w owns rows w*16..w*16+15. Each lane loads ONE float of each
//          row (coalesced 256B/row, all 16 issued upfront), then readlane
//          broadcasts feed per-unit FMA chains. Rows processed in pairs so the
//          two acc chains saturate VALU issue. No LDS, no latency exposure.
//  phase2a: lane=row; wave g computes enc dims 4g..4g+3 (sh stride 65,
//          se stride 17: conflict-free).
//  phase2b: lane=row; wave g computes qkv outputs 12g..12g+11 and stores them
//          as 3 coalesced float4 stores (fixes r3's 15x write amplification).
// Q pre-scaled by 0.5*log2(e) so attention uses raw exp2.
// ---------------------------------------------------------------------------
__global__ __launch_bounds__(256, 4) void enc_qkv_kernel(
    const float* __restrict__ board, const float* __restrict__ w1,
    const float* __restrict__ b1, const float* __restrict__ w2,
    const float* __restrict__ b2, const float* __restrict__ w_qkv,
    const float* __restrict__ b_qkv,
    float* __restrict__ Q, float* __restrict__ K, float* __restrict__ V)
{
    __shared__ float sh[64 * 65];    // h, stride 65 (conflict-free)
    __shared__ float se[64 * 17];    // enc, stride 17 (conflict-free)

    const int tid  = threadIdx.x;
    const int w    = tid >> 6;       // wave id 0..3
    const int lane = tid & 63;
    const int row0 = blockIdx.x * 64;

    // ---- phase 1: h = relu(feats @ w1 + b1); lane = hidden unit ----
    {
        float wcol[66];
        #pragma unroll
        for (int i = 0; i < 66; ++i) wcol[i] = w1[i * 64 + lane];
        const float bias1 = b1[lane];

        // Coalesced: lane loads element `lane` of each of the wave's 16 rows.
        float fv[16];
        #pragma unroll
        for (int r = 0; r < 16; ++r)
            fv[r] = board[(size_t)(row0 + w * 16 + r) * 64 + lane];

        #pragma unroll
        for (int r = 0; r < 16; r += 2) {
            const int rowA = row0 + w * 16 + r;
            const int rowB = rowA + 1;
            const int bA = rowA / Ll, lA = rowA - bA * Ll;
            const int bB = rowB / Ll, lB = rowB - bB * Ll;
            const int dA = lA / Pp, pA = lA - dA * Pp;
            const int dB = lB / Pp, pB = lB - dB * Pp;
            float accA = bias1, accB = bias1;
            #pragma unroll
            for (int i = 0; i < 64; ++i) {
                accA = fmaf(lane_bcast(fv[r],     i), wcol[i], accA);
                accB = fmaf(lane_bcast(fv[r + 1], i), wcol[i], accB);
            }
            accA = fmaf((float)pA, wcol[64], accA);
            accB = fmaf((float)pB, wcol[64], accB);
            accA = fmaf((float)dA, wcol[65], accA);
            accB = fmaf((float)dB, wcol[65], accB);
            sh[(w * 16 + r)     * 65 + lane] = fmaxf(accA, 0.f);
            sh[(w * 16 + r + 1) * 65 + lane] = fmaxf(accB, 0.f);
        }
    }
    __syncthreads();

    // ---- phase 2a: enc dims 4w..4w+3 for all 64 rows; lane = row ----
    {
        float4 e4 = ((const float4*)b2)[w];
        const float4* w2v = (const float4*)w2;
        #pragma unroll 4
        for (int j = 0; j < 64; ++j) {
            const float hj = sh[lane * 65 + j];       // conflict-free
            const float4 w4 = w2v[j * 4 + w];         // broadcast, L1-hot
            e4.x = fmaf(hj, w4.x, e4.x);
            e4.y = fmaf(hj, w4.y, e4.y);
            e4.z = fmaf(hj, w4.z, e4.z);
            e4.w = fmaf(hj, w4.w, e4.w);
        }
        se[lane * 17 + 4 * w + 0] = e4.x;
        se[lane * 17 + 4 * w + 1] = e4.y;
        se[lane * 17 + 4 * w + 2] = e4.z;
        se[lane * 17 + 4 * w + 3] = e4.w;
    }
    __syncthreads();

    // ---- phase 2b: lane = row; wave w -> qkv outputs 12w..12w+11 ----
    {
        float x[16];
        #pragma unroll
        for (int e = 0; e < 16; ++e) x[e] = se[lane * 17 + e];

        const int row = row0 + lane;
        const int b   = row / Ll;
        const int l   = row - b * Ll;

        float res[12];
        #pragma unroll
        for (int jj = 0; jj < 12; ++jj) {
            const int j = 12 * w + jj;
            const float4* wr = (const float4*)(w_qkv + j * 16);
            const float4 x0 = wr[0], x1 = wr[1], x2 = wr[2], x3 = wr[3];
            float a = b_qkv[j];
            a = fmaf(x[0],  x0.x, a); a = fmaf(x[1],  x0.y, a);
            a = fmaf(x[2],  x0.z, a); a = fmaf(x[3],  x0.w, a);
            a = fmaf(x[4],  x1.x, a); a = fmaf(x[5],  x1.y, a);
            a = fmaf(x[6],  x1.z, a); a = fmaf(x[7],  x1.w, a);
            a = fmaf(x[8],  x2.x, a); a = fmaf(x[9],  x2.y, a);
            a = fmaf(x[10], x2.z, a); a = fmaf(x[11], x2.w, a);
            a = fmaf(x[12], x3.x, a); a = fmaf(x[13], x3.y, a);
            a = fmaf(x[14], x3.z, a); a = fmaf(x[15], x3.w, a);
            res[jj] = a;
        }

        const float SC = 0.72134752044f;   // 0.5 * log2(e)
        #pragma unroll
        for (int m3 = 0; m3 < 3; ++m3) {
            const int m = 3 * w + m3;          // float4 group: tensor*4 + h
            const int tensor = m >> 2;
            const int h = m & 3;
            float4 vv = make_float4(res[4*m3+0], res[4*m3+1],
                                    res[4*m3+2], res[4*m3+3]);
            if (tensor == 0) { vv.x *= SC; vv.y *= SC; vv.z *= SC; vv.w *= SC; }
            float* basep = (tensor == 0) ? Q : (tensor == 1) ? K : V;
            // lane = row -> consecutive l -> coalesced 1KB float4 store
            *(float4*)(basep + (((size_t)(b * Hh + h)) * Ll + l) * HDim) = vv;
        }
    }
}

// ---------------------------------------------------------------------------
// Kernel B: attention, no LDS. Thread = (bh, q-row), flat over 512*416.
// K/V rows are wave-uniform float4 loads (1 L1/L2 transaction per instr);
// VALU-bound inner loop: 4 FMA dot + exp2 + 5 FMA accum per key.
// Max-free single-pass softmax (scores tiny; softmax shift-invariant).
// ---------------------------------------------------------------------------
__global__ __launch_bounds__(256, 8) void attn_kernel(
    const float* __restrict__ Q, const float* __restrict__ K,
    const float* __restrict__ V, float* __restrict__ ATT)
{
    const int flat = blockIdx.x * 256 + threadIdx.x;   // bh*Ll + qi
    const int bh = flat / Ll;
    const int qi = flat - bh * Ll;

    const float4 q = ((const float4*)Q)[flat];
    const float4* __restrict__ Kb = (const float4*)K + (size_t)bh * Ll;
    const float4* __restrict__ Vb = (const float4*)V + (size_t)bh * Ll;

    float s = 0.f;
    float4 o = make_float4(0.f, 0.f, 0.f, 0.f);

    #pragma unroll 4
    for (int l = 0; l < Ll; ++l) {
        const float4 k = Kb[l];          // wave-uniform -> 1 transaction
        const float4 v = Vb[l];
        float dot = q.x * k.x;
        dot = fmaf(q.y, k.y, dot);
        dot = fmaf(q.z, k.z, dot);
        dot = fmaf(q.w, k.w, dot);
        const float e = __builtin_amdgcn_exp2f(dot);
        s += e;
        o.x = fmaf(e, v.x, o.x);
        o.y = fmaf(e, v.y, o.y);
        o.z = fmaf(e, v.z, o.z);
        o.w = fmaf(e, v.w, o.w);
    }

    const int b = bh >> 2;
    const int h = bh & 3;
    const float inv = 1.0f / s;
    *(float4*)(ATT + ((size_t)(b * Ll + qi)) * Ee + h * HDim) =
        make_float4(o.x * inv, o.y * inv, o.z * inv, o.w * inv);
}

// ---------------------------------------------------------------------------
// Kernel C: out projection (16x16 GEMV per row; LDS-transposed w_out).
// ---------------------------------------------------------------------------
__global__ __launch_bounds__(256, 8) void outproj_kernel(
    const float* __restrict__ ATT, const float* __restrict__ w_out,
    const float* __restrict__ b_out, float* __restrict__ out)
{
    __shared__ float sx[256];
    __shared__ float sw[256];   // sw[e*16+o] = w_out[o*16+e]

    const int tid = threadIdx.x;
    const size_t gbase = (size_t)blockIdx.x * 256;
    sx[tid] = ATT[gbase + tid];
    sw[tid] = w_out[(tid & 15) * 16 + (tid >> 4)];
    __syncthreads();

    const int rloc = tid >> 4;
    const int o = tid & 15;
    float acc = b_out[o];
    #pragma unroll
    for (int e = 0; e < 16; ++e)
        acc = fmaf(sx[rloc * 16 + e], sw[e * 16 + o], acc);
    out[gbase + tid] = acc;
}

// ---------------------------------------------------------------------------
extern "C" void kernel_launch(void* const* d_in, const int* in_sizes, int n_in,
                              void* d_out, int out_size, void* d_ws, size_t ws_size,
                              hipStream_t stream) {
    const float* board = (const float*)d_in[0];
    const float* w1    = (const float*)d_in[1];
    const float* b1    = (const float*)d_in[2];
    const float* w2    = (const float*)d_in[3];
    const float* b2    = (const float*)d_in[4];
    const float* w_qkv = (const float*)d_in[5];
    const float* b_qkv = (const float*)d_in[6];
    const float* w_out = (const float*)d_in[7];
    const float* b_out = (const float*)d_in[8];
    float* out = (float*)d_out;

    float* ws  = (float*)d_ws;
    float* Q   = ws;                        // (B,H,L,HD)
    float* K   = ws + (size_t)Rr * Ee;
    float* V   = ws + (size_t)2 * Rr * Ee;
    float* ATT = ws + (size_t)3 * Rr * Ee;  // (B,L,E)

    hipLaunchKernelGGL(enc_qkv_kernel, dim3(Rr / 64), dim3(256), 0, stream,
                       board, w1, b1, w2, b2, w_qkv, b_qkv, Q, K, V);
    hipLaunchKernelGGL(attn_kernel, dim3(Rr * Hh / 256), dim3(256), 0, stream,
                       Q, K, V, ATT);
    hipLaunchKernelGGL(outproj_kernel, dim3((Rr * Ee) / 256), dim3(256), 0, stream,
                       ATT, w_out, b_out, out);
}

// Round 5
// 142.907 us; speedup vs baseline: 1.7740x; 1.4483x over previous
//
#include <hip/hip_runtime.h>

#define Bn 128
#define Dd 32
#define Pp 13
#define Ee 16
#define Hh 4
#define HDim 4
#define Ll 416           // Dd*Pp
#define Rr (Bn*Ll)       // 53248 rows

// Broadcast lane i's value to all lanes (v_readlane -> SGPR operand).
__device__ __forceinline__ float lane_bcast(float x, int i) {
    return __uint_as_float(__builtin_amdgcn_readlane(__float_as_uint(x), i));
}

// ---------------------------------------------------------------------------
// Kernel A: fused encoder + QKV (unchanged from r4 — FETCH/WRITE now ideal).
// ---------------------------------------------------------------------------
__global__ __launch_bounds__(256, 4) void enc_qkv_kernel(
    const float* __restrict__ board, const float* __restrict__ w1,
    const float* __restrict__ b1, const float* __restrict__ w2,
    const float* __restrict__ b2, const float* __restrict__ w_qkv,
    const float* __restrict__ b_qkv,
    float* __restrict__ Q, float* __restrict__ K, float* __restrict__ V)
{
    __shared__ float sh[64 * 65];    // h, stride 65 (conflict-free)
    __shared__ float se[64 * 17];    // enc, stride 17 (conflict-free)

    const int tid  = threadIdx.x;
    const int w    = tid >> 6;       // wave id 0..3
    const int lane = tid & 63;
    const int row0 = blockIdx.x * 64;

    // ---- phase 1: h = relu(feats @ w1 + b1); lane = hidden unit ----
    {
        float wcol[66];
        #pragma unroll
        for (int i = 0; i < 66; ++i) wcol[i] = w1[i * 64 + lane];
        const float bias1 = b1[lane];

        float fv[16];
        #pragma unroll
        for (int r = 0; r < 16; ++r)
            fv[r] = board[(size_t)(row0 + w * 16 + r) * 64 + lane];

        #pragma unroll
        for (int r = 0; r < 16; r += 2) {
            const int rowA = row0 + w * 16 + r;
            const int rowB = rowA + 1;
            const int bA = rowA / Ll, lA = rowA - bA * Ll;
            const int bB = rowB / Ll, lB = rowB - bB * Ll;
            const int dA = lA / Pp, pA = lA - dA * Pp;
            const int dB = lB / Pp, pB = lB - dB * Pp;
            float accA = bias1, accB = bias1;
            #pragma unroll
            for (int i = 0; i < 64; ++i) {
                accA = fmaf(lane_bcast(fv[r],     i), wcol[i], accA);
                accB = fmaf(lane_bcast(fv[r + 1], i), wcol[i], accB);
            }
            accA = fmaf((float)pA, wcol[64], accA);
            accB = fmaf((float)pB, wcol[64], accB);
            accA = fmaf((float)dA, wcol[65], accA);
            accB = fmaf((float)dB, wcol[65], accB);
            sh[(w * 16 + r)     * 65 + lane] = fmaxf(accA, 0.f);
            sh[(w * 16 + r + 1) * 65 + lane] = fmaxf(accB, 0.f);
        }
    }
    __syncthreads();

    // ---- phase 2a: enc dims 4w..4w+3 for all 64 rows; lane = row ----
    {
        float4 e4 = ((const float4*)b2)[w];
        const float4* w2v = (const float4*)w2;
        #pragma unroll 4
        for (int j = 0; j < 64; ++j) {
            const float hj = sh[lane * 65 + j];
            const float4 w4 = w2v[j * 4 + w];
            e4.x = fmaf(hj, w4.x, e4.x);
            e4.y = fmaf(hj, w4.y, e4.y);
            e4.z = fmaf(hj, w4.z, e4.z);
            e4.w = fmaf(hj, w4.w, e4.w);
        }
        se[lane * 17 + 4 * w + 0] = e4.x;
        se[lane * 17 + 4 * w + 1] = e4.y;
        se[lane * 17 + 4 * w + 2] = e4.z;
        se[lane * 17 + 4 * w + 3] = e4.w;
    }
    __syncthreads();

    // ---- phase 2b: lane = row; wave w -> qkv outputs 12w..12w+11 ----
    {
        float x[16];
        #pragma unroll
        for (int e = 0; e < 16; ++e) x[e] = se[lane * 17 + e];

        const int row = row0 + lane;
        const int b   = row / Ll;
        const int l   = row - b * Ll;

        float res[12];
        #pragma unroll
        for (int jj = 0; jj < 12; ++jj) {
            const int j = 12 * w + jj;
            const float4* wr = (const float4*)(w_qkv + j * 16);
            const float4 x0 = wr[0], x1 = wr[1], x2 = wr[2], x3 = wr[3];
            float a = b_qkv[j];
            a = fmaf(x[0],  x0.x, a); a = fmaf(x[1],  x0.y, a);
            a = fmaf(x[2],  x0.z, a); a = fmaf(x[3],  x0.w, a);
            a = fmaf(x[4],  x1.x, a); a = fmaf(x[5],  x1.y, a);
            a = fmaf(x[6],  x1.z, a); a = fmaf(x[7],  x1.w, a);
            a = fmaf(x[8],  x2.x, a); a = fmaf(x[9],  x2.y, a);
            a = fmaf(x[10], x2.z, a); a = fmaf(x[11], x2.w, a);
            a = fmaf(x[12], x3.x, a); a = fmaf(x[13], x3.y, a);
            a = fmaf(x[14], x3.z, a); a = fmaf(x[15], x3.w, a);
            res[jj] = a;
        }

        const float SC = 0.72134752044f;   // 0.5 * log2(e)
        #pragma unroll
        for (int m3 = 0; m3 < 3; ++m3) {
            const int m = 3 * w + m3;          // float4 group: tensor*4 + h
            const int tensor = m >> 2;
            const int h = m & 3;
            float4 vv = make_float4(res[4*m3+0], res[4*m3+1],
                                    res[4*m3+2], res[4*m3+3]);
            if (tensor == 0) { vv.x *= SC; vv.y *= SC; vv.z *= SC; vv.w *= SC; }
            float* basep = (tensor == 0) ? Q : (tensor == 1) ? K : V;
            *(float4*)(basep + (((size_t)(b * Hh + h)) * Ll + l) * HDim) = vv;
        }
    }
}

// ---------------------------------------------------------------------------
// Kernel B: attention. Block = (bh, half): K/V addresses are blockIdx-derived
// -> provably wave-uniform + noclobber (__restrict__, only ATT written) ->
// compiler selects SMEM s_load for K/V (constant-cache, lgkmcnt pipe, cheap
// prefetch). 8-key register batches give 16 loads in flight even on the VMEM
// fallback path. 208 active threads x (512,2) grid = 16 waves/CU.
// Max-free single-pass softmax (scores tiny; softmax shift-invariant).
// ---------------------------------------------------------------------------
__global__ __launch_bounds__(256, 8) void attn_kernel(
    const float* __restrict__ Q, const float* __restrict__ K,
    const float* __restrict__ V, float* __restrict__ ATT)
{
    const int bh   = blockIdx.x;          // b*Hh + h
    const int half = blockIdx.y;          // 0/1
    const int tid  = threadIdx.x;
    if (tid >= 208) return;
    const int qi = half * 208 + tid;      // 0..415 across the two halves

    const float4* __restrict__ Kb = (const float4*)K + (size_t)bh * Ll;
    const float4* __restrict__ Vb = (const float4*)V + (size_t)bh * Ll;
    const float4 q = ((const float4*)Q + (size_t)bh * Ll)[qi];

    float s = 0.f;
    float4 o = make_float4(0.f, 0.f, 0.f, 0.f);

    for (int l0 = 0; l0 < Ll; l0 += 8) {   // 416 = 52*8
        float4 kk[8], vv[8];
        #pragma unroll
        for (int j = 0; j < 8; ++j) { kk[j] = Kb[l0 + j]; vv[j] = Vb[l0 + j]; }
        #pragma unroll
        for (int j = 0; j < 8; ++j) {
            float dot = q.x * kk[j].x;
            dot = fmaf(q.y, kk[j].y, dot);
            dot = fmaf(q.z, kk[j].z, dot);
            dot = fmaf(q.w, kk[j].w, dot);
            const float e = __builtin_amdgcn_exp2f(dot);
            s += e;
            o.x = fmaf(e, vv[j].x, o.x);
            o.y = fmaf(e, vv[j].y, o.y);
            o.z = fmaf(e, vv[j].z, o.z);
            o.w = fmaf(e, vv[j].w, o.w);
        }
    }

    const int b = bh >> 2;
    const int h = bh & 3;
    const float inv = 1.0f / s;
    *(float4*)(ATT + ((size_t)(b * Ll + qi)) * Ee + h * HDim) =
        make_float4(o.x * inv, o.y * inv, o.z * inv, o.w * inv);
}

// ---------------------------------------------------------------------------
// Kernel C: out projection (16x16 GEMV per row; LDS-transposed w_out).
// ---------------------------------------------------------------------------
__global__ __launch_bounds__(256, 8) void outproj_kernel(
    const float* __restrict__ ATT, const float* __restrict__ w_out,
    const float* __restrict__ b_out, float* __restrict__ out)
{
    __shared__ float sx[256];
    __shared__ float sw[256];   // sw[e*16+o] = w_out[o*16+e]

    const int tid = threadIdx.x;
    const size_t gbase = (size_t)blockIdx.x * 256;
    sx[tid] = ATT[gbase + tid];
    sw[tid] = w_out[(tid & 15) * 16 + (tid >> 4)];
    __syncthreads();

    const int rloc = tid >> 4;
    const int o = tid & 15;
    float acc = b_out[o];
    #pragma unroll
    for (int e = 0; e < 16; ++e)
        acc = fmaf(sx[rloc * 16 + e], sw[e * 16 + o], acc);
    out[gbase + tid] = acc;
}

// ---------------------------------------------------------------------------
extern "C" void kernel_launch(void* const* d_in, const int* in_sizes, int n_in,
                              void* d_out, int out_size, void* d_ws, size_t ws_size,
                              hipStream_t stream) {
    const float* board = (const float*)d_in[0];
    const float* w1    = (const float*)d_in[1];
    const float* b1    = (const float*)d_in[2];
    const float* w2    = (const float*)d_in[3];
    const float* b2    = (const float*)d_in[4];
    const float* w_qkv = (const float*)d_in[5];
    const float* b_qkv = (const float*)d_in[6];
    const float* w_out = (const float*)d_in[7];
    const float* b_out = (const float*)d_in[8];
    float* out = (float*)d_out;

    float* ws  = (float*)d_ws;
    float* Q   = ws;                        // (B,H,L,HD)
    float* K   = ws + (size_t)Rr * Ee;
    float* V   = ws + (size_t)2 * Rr * Ee;
    float* ATT = ws + (size_t)3 * Rr * Ee;  // (B,L,E)

    hipLaunchKernelGGL(enc_qkv_kernel, dim3(Rr / 64), dim3(256), 0, stream,
                       board, w1, b1, w2, b2, w_qkv, b_qkv, Q, K, V);
    hipLaunchKernelGGL(attn_kernel, dim3(Bn * Hh, 2), dim3(256), 0, stream,
                       Q, K, V, ATT);
    hipLaunchKernelGGL(outproj_kernel, dim3((Rr * Ee) / 256), dim3(256), 0, stream,
                       ATT, w_out, b_out, out);
}